// Round 10
// baseline (181.732 us; speedup 1.0000x reference)
//
#include <hip/hip_runtime.h>
#include <math.h>

#define B_ 4
#define S_ 2048
#define D_ 128
#define EPSF 1e-5f
#define BN 128
#define PRS 4128    // tier2 P_row stride bytes
#define PS2 136     // tier1 Ps row stride (64 bf16 + 8B shift)

typedef __attribute__((ext_vector_type(8))) short short8;
typedef __attribute__((ext_vector_type(4))) float f32x4;

static __device__ __forceinline__ unsigned short f2bf(float f) {
    unsigned u = __float_as_uint(f);
    return (unsigned short)((u + 0x7fffu + ((u >> 16) & 1u)) >> 16);
}

static __device__ __forceinline__ void gload_lds16(const void* g, void* l) {
    __builtin_amdgcn_global_load_lds((const __attribute__((address_space(1))) unsigned*)g,
                                     (__attribute__((address_space(3))) unsigned*)l, 16, 0, 0);
}

// ===================== pre-pass kernels =====================
// KbA: frag-native per 64-key tile (16 KB): byte = t64*16384 + ks*4096 + n*64 + quad*16
//   (n = key 0..63 within tile, k-dim = ks*32 + quad*8 + j). Wave B-frag load = contiguous.
// Vtb: frag-native per 128-key tile (32 KB): byte = kq*8192 + d*64 + quad*16.
// ws: [96K,160K) qng, [160K,224K) kng, [64K,96K) lws,
//     @224K: Qb(2M) KbA(2M) Vtb(2M) | Opart(16.8M) Pws(33.5M)

__global__ __launch_bounds__(256) void convqk_kernel(const float* __restrict__ q,
                                                     const float* __restrict__ k,
                                                     const float* __restrict__ cp,
                                                     float* __restrict__ lws,
                                                     float2* __restrict__ qng, float2* __restrict__ kng,
                                                     unsigned* __restrict__ Qb, unsigned* __restrict__ KbA) {
    int row = blockIdx.x * 4 + (threadIdx.x >> 6);   // one wave per row, 16384 rows
    int lane = threadIdx.x & 63;
    const int NR = B_ * S_;
    const float cc = cp[0];
    bool isQ = row < NR;
    int r = isQ ? row : row - NR;
    float2 v = ((const float2*)(isQ ? q : k))[(size_t)r * 64 + lane];
    unsigned pk = (unsigned)f2bf(v.x) | ((unsigned)f2bf(v.y) << 16);
    float nrm = v.x * v.x + v.y * v.y;
#pragma unroll
    for (int m = 1; m <= 32; m <<= 1) nrm += __shfl_xor(nrm, m, 64);
    if (isQ) {
        Qb[(size_t)r * 64 + lane] = pk;              // row-major
        if (lane == 0)
            qng[r] = make_float2(nrm, 2.f * cc * __builtin_amdgcn_rcpf(1.f - cc * nrm));
        if (lane == 1) lws[r] = 0.f;                 // zero l accumulator (tier1 atomics)
    } else {
        // pair index lane -> ks = lane>>4, quad = (lane>>2)&3, slot = lane&3
        int b = r >> 11, rloc = r & 2047;
        int t64 = rloc >> 6, n = rloc & 63;
        KbA[(size_t)b * 131072 + t64 * 4096 + (lane >> 4) * 1024 + n * 16 +
            ((lane >> 2) & 3) * 4 + (lane & 3)] = pk;
        if (lane == 0)
            kng[r] = make_float2(nrm, __builtin_amdgcn_rcpf(1.f - cc * nrm));
    }
}

__global__ __launch_bounds__(256) void convv_kernel(const float* __restrict__ v, uint4* __restrict__ Vtb) {
    __shared__ unsigned short Vs[128 * 132];
    int b = blockIdx.x >> 4;
    int t = blockIdx.x & 15;
    int tid = threadIdx.x;
    const float* src = v + ((size_t)b * S_ + t * 128) * D_;
    int d4 = tid & 31, key0 = tid >> 5;
#pragma unroll
    for (int it = 0; it < 16; ++it) {
        int key = key0 + it * 8;
        float4 f = *(const float4*)(src + (size_t)key * D_ + d4 * 4);
        unsigned short* dst = &Vs[key * 132 + d4 * 4];
        dst[0] = f2bf(f.x); dst[1] = f2bf(f.y); dst[2] = f2bf(f.z); dst[3] = f2bf(f.w);
    }
    __syncthreads();
    uint4* tile = Vtb + (size_t)blockIdx.x * (128 * 16);   // [kq][d][quad]
    int d = tid & 127;
    int cl = tid >> 7;
#pragma unroll
    for (int it = 0; it < 8; ++it) {
        int c = cl + it * 2;                          // k-octet 0..15
        int kb = c * 8;
        unsigned short e0 = Vs[(kb + 0) * 132 + d], e1 = Vs[(kb + 1) * 132 + d];
        unsigned short e2 = Vs[(kb + 2) * 132 + d], e3 = Vs[(kb + 3) * 132 + d];
        unsigned short e4 = Vs[(kb + 4) * 132 + d], e5 = Vs[(kb + 5) * 132 + d];
        unsigned short e6 = Vs[(kb + 6) * 132 + d], e7 = Vs[(kb + 7) * 132 + d];
        uint4 o;
        o.x = (unsigned)e0 | ((unsigned)e1 << 16);
        o.y = (unsigned)e2 | ((unsigned)e3 << 16);
        o.z = (unsigned)e4 | ((unsigned)e5 << 16);
        o.w = (unsigned)e6 | ((unsigned)e7 << 16);
        tile[(c >> 2) * 512 + d * 4 + (c & 3)] = o;
    }
}

// ===================== v11: quarter-split LDS-staged loop, high occupancy =====================
// Grid 1024 (256 row-blocks x 4 key-quarters), 512 threads / 8 waves, 32 q-rows x 512 keys.
// BN=64 K-tiles double-buffered via global_load_lds (16 KB/iter); V frags direct-global
// (hidden under dist); P stripe 4.4 KB; 2 barriers/iter, 8 iters. LDS 37.4 KB -> 4 blocks/CU.
// Outputs: unnormalized bf16 P -> Pws (coalesced per-iter), partial O -> Opart[qtr],
// l -> global lws atomics. hepi4 combines; wnorm2 normalizes W.
//
// LDS: Ks[2] @0/16384, Ps @32768 (32 x 136), xr @37120 (32 float2) -> 37376 B.

__global__ __launch_bounds__(512, 6) void hattn11_kernel(
    const unsigned short* __restrict__ Qb, const char* __restrict__ KbA,
    const char* __restrict__ Vtb,
    const float2* __restrict__ qng, const float2* __restrict__ kng,
    const float* __restrict__ cp, const float* __restrict__ betap, const float* __restrict__ biasp,
    float* __restrict__ lws, float* __restrict__ Opart, uint4* __restrict__ Pws) {

    __shared__ __align__(1024) char smem[37376];
    char* PsB = smem + 32768;
    float2* xr_s = (float2*)(smem + 37120);

    const int tid = threadIdx.x;
    const int lane = tid & 63, wave = tid >> 6;      // 8 waves
    const int wm = wave & 1, wn = wave >> 1;         // wm: 16-row half; wn: 16-col slice (0..3)
    const int lm = lane & 15, quad = lane >> 4;

    const int qtr = blockIdx.x & 3;                  // key quarter
    const int rid = blockIdx.x >> 2;                 // 0..255
    const int b = rid & 3;
    const int rb = rid >> 2;                         // 0..63
    const int s0 = rb * 32;
    const size_t bS = (size_t)b * S_;

    const float beta = betap[0], bias = biasp[0];
    const float cc = cp[0];
    const float beta_pos = fmaxf(beta, 0.f) + log1pf(__expf(-fabsf(beta)));
    const float sqrt_c = sqrtf(cc);
    const float bneg = -beta_pos / sqrt_c;           // p = 2^(bneg*log2(w) + bias2)
    const float bias2 = -bias * 1.442695040888963f;
    const float onepe = 1.f + EPSF;
    (void)sqrt_c;

    const char* KA = KbA + (size_t)b * 524288 + (size_t)qtr * (8 * 16384);
    const char* Vt = Vtb + (size_t)b * 524288;

    if (tid < 32) xr_s[tid] = qng[bS + s0 + tid];

    // stage K tile 0 into buffer 0 (16 KB linear)
#pragma unroll
    for (int j = 0; j < 2; ++j) {
        int off = (tid + j * 512) * 16;
        gload_lds16(KA + off, smem + off);
    }

    short8 aq[4];                                    // A-frag: q-row = wm*16+lm
    {
        const unsigned short* qrow = Qb + (bS + s0 + wm * 16 + lm) * D_;
#pragma unroll
        for (int ks = 0; ks < 4; ++ks)
            aq[ks] = *(const short8*)(qrow + ks * 32 + quad * 8);
    }
    __syncthreads();   // stage + xr drained

    f32x4 o0 = {0.f, 0.f, 0.f, 0.f}, o1 = {0.f, 0.f, 0.f, 0.f};
    float lacc[4] = {0.f, 0.f, 0.f, 0.f};
    int p = 0;
    const int col = wn * 16 + lm;                    // key col within 64-tile

    for (int it = 0; it < 8; ++it) {
        char* KsC = smem + p * 16384;

        // stage next K tile into back buffer (hidden under QK + dist)
        if (it < 7) {
            const char* ks = KA + (size_t)(it + 1) * 16384;
            char* kd = smem + (p ^ 1) * 16384;
#pragma unroll
            for (int j = 0; j < 2; ++j) {
                int off = (tid + j * 512) * 16;
                gload_lds16(ks + off, kd + off);
            }
        }

        // ---- S = Q K^T (wave tile 16x16) from LDS ----
        f32x4 acc = {0.f, 0.f, 0.f, 0.f};
        {
            const char* kb = KsC + col * 64 + quad * 16;
#pragma unroll
            for (int ks = 0; ks < 4; ++ks) {
                short8 bk = *(const short8*)(kb + ks * 4096);
                acc = __builtin_amdgcn_mfma_f32_16x16x32_bf16(aq[ks], bk, acc, 0, 0, 0);
            }
        }

        // ---- V frags direct-global (latency hidden under dist chain) ----
        const char* vbase = Vt + (size_t)(qtr * 4 + (it >> 1)) * 32768
                            + wn * 2048 + lm * 64 + quad * 16;
        const int kqb = (it & 1) * 2;
        short8 vf00 = *(const short8*)(vbase + (kqb + 0) * 8192);
        short8 vf01 = *(const short8*)(vbase + (kqb + 1) * 8192);
        short8 vf10 = *(const short8*)(vbase + (kqb + 0) * 8192 + 1024);
        short8 vf11 = *(const short8*)(vbase + (kqb + 1) * 8192 + 1024);

        // ---- dist -> p (4 elements), P -> Ps stripe ----
        {
            float2 yg = kng[bS + qtr * 512 + it * 64 + col];
#pragma unroll
            for (int r = 0; r < 4; ++r) {
                int row = wm * 16 + quad * 4 + r;
                float2 xr = xr_s[row];
                float diff = fmaf(-2.f, acc[r], xr.x + yg.x);
                float arg = fmaxf(fmaf(diff * yg.y, xr.y, 1.f), onepe);
                float w = arg + sqrtf(fmaf(arg, arg, -1.f));
                float pv = __builtin_amdgcn_exp2f(fmaf(bneg, __builtin_amdgcn_logf(w), bias2));
                *(unsigned short*)(PsB + row * PS2 + col * 2) = f2bf(pv);
                lacc[r] += pv;
            }
        }
        __syncthreads();   // A: Ps ready; K back staged; V frags drained

        // ---- unnormalized bf16 P tile -> Pws (32x64 = 4 KB) ----
        if (tid < 256) {
            int row = tid >> 3, ch = tid & 7;
            uint4 u = *(const uint4*)(PsB + row * PS2 + ch * 16);
            Pws[(((bS + s0 + row) * S_ + qtr * 512 + it * 64) >> 3) + ch] = u;
        }

        // ---- O += P V (wave tile 16 rows x 32 d) ----
        {
            const char* pr = PsB + (wm * 16 + lm) * PS2 + quad * 16;
#pragma unroll
            for (int kq = 0; kq < 2; ++kq) {
                short8 ap = *(const short8*)(pr + kq * 64);
                o0 = __builtin_amdgcn_mfma_f32_16x16x32_bf16(ap, kq ? vf01 : vf00, o0, 0, 0, 0);
                o1 = __builtin_amdgcn_mfma_f32_16x16x32_bf16(ap, kq ? vf11 : vf10, o1, 0, 0, 0);
            }
        }
        __syncthreads();   // B: Ps readers done; safe to overwrite next iter
        p ^= 1;
    }

    // ---- l: shfl-reduce over cols, one global atomic per (wave,row) ----
#pragma unroll
    for (int r = 0; r < 4; ++r) {
        float s = lacc[r];
#pragma unroll
        for (int m = 1; m <= 8; m <<= 1) s += __shfl_xor(s, m, 64);
        if (lm == 0) atomicAdd(&lws[bS + s0 + wm * 16 + quad * 4 + r], s);
    }

    // ---- partial O (unnormalized) ----
    float* op = Opart + (size_t)qtr * (B_ * S_ * D_) + (bS + s0) * D_;
#pragma unroll
    for (int r = 0; r < 4; ++r) {
        int row = wm * 16 + quad * 4 + r;
        op[(size_t)row * D_ + wn * 32 + lm] = o0[r];
        op[(size_t)row * D_ + wn * 32 + 16 + lm] = o1[r];
    }
}

// combine 4 partial O's, normalize, exp-map
__global__ __launch_bounds__(256) void hepi4_kernel(const float* __restrict__ Opart,
                                                    const float* __restrict__ lws,
                                                    const float* __restrict__ cp,
                                                    float* __restrict__ hout) {
    int row = blockIdx.x * 4 + (threadIdx.x >> 6);   // one wave per row
    int lane = threadIdx.x & 63;
    const int NP = B_ * S_ * D_;
    const float cc = cp[0];
    const float sqrt_c = sqrtf(cc);
    float2 a0 = ((const float2*)(Opart + (size_t)row * D_))[lane];
    float2 a1 = ((const float2*)(Opart + (size_t)NP + (size_t)row * D_))[lane];
    float2 a2 = ((const float2*)(Opart + (size_t)2 * NP + (size_t)row * D_))[lane];
    float2 a3 = ((const float2*)(Opart + (size_t)3 * NP + (size_t)row * D_))[lane];
    float linv = 1.f / lws[row];
    float x0 = (a0.x + a1.x + a2.x + a3.x) * linv;
    float x1 = (a0.y + a1.y + a2.y + a3.y) * linv;
    float np = x0 * x0 + x1 * x1;
#pragma unroll
    for (int m = 1; m <= 32; m <<= 1) np += __shfl_xor(np, m, 64);
    float vn = fmaxf(sqrtf(np), EPSF);
    float aa = sqrt_c * vn;
    float t = 1.f - 2.f / (__expf(2.f * aa) + 1.f);  // tanh(aa)
    float sc = t / aa;
    float2 o = {x0 * sc, x1 * sc};
    ((float2*)(hout + (size_t)row * D_))[lane] = o;
}

// expand bf16 P -> normalized fp32 W
__global__ __launch_bounds__(256) void wnorm2_kernel(const uint4* __restrict__ Pws,
                                                     const float* __restrict__ lws,
                                                     float* __restrict__ w) {
    size_t idx = (size_t)blockIdx.x * 256 + threadIdx.x;   // uint4 index (8 bf16)
    int row = (int)(idx >> 8);                             // 256 uint4 per row
    float linv = 1.f / lws[row];
    uint4 u = Pws[idx];
    float4 f0, f1;
    f0.x = __uint_as_float(u.x << 16) * linv;
    f0.y = __uint_as_float(u.x & 0xffff0000u) * linv;
    f0.z = __uint_as_float(u.y << 16) * linv;
    f0.w = __uint_as_float(u.y & 0xffff0000u) * linv;
    f1.x = __uint_as_float(u.z << 16) * linv;
    f1.y = __uint_as_float(u.z & 0xffff0000u) * linv;
    f1.z = __uint_as_float(u.w << 16) * linv;
    f1.w = __uint_as_float(u.w & 0xffff0000u) * linv;
    float4* out = (float4*)w + idx * 2;
    out[0] = f0;
    out[1] = f1;
}

// ===================== tier-2 fallback: proven v8 structure (137.8 total), KbA64 addressing =====================

__global__ __launch_bounds__(512, 4) void hattn8_kernel(
    const unsigned short* __restrict__ Qb, const char* __restrict__ KbA,
    const char* __restrict__ Vtb,
    const float2* __restrict__ qng, const float2* __restrict__ kng,
    const float* __restrict__ cp, const float* __restrict__ betap, const float* __restrict__ biasp,
    float* __restrict__ hout, float* __restrict__ wout) {

    __shared__ __align__(1024) char smem[66304];
    float* l_row = (float*)(smem + 66176);
    float* nsq_s = (float*)(smem + 66240);

    const int tid = threadIdx.x;
    const int lane = tid & 63, wave = tid >> 6;
    const int wn = wave;
    const int lm = lane & 15, quad = lane >> 4;

    int xcd = blockIdx.x & 7;
    int b = xcd >> 1;
    int rb = (blockIdx.x >> 3) * 2 + (xcd & 1);
    int s0 = rb * 16;
    const size_t bS = (size_t)b * S_;

    const float beta = betap[0], bias = biasp[0];
    const float cc = cp[0];
    const float beta_pos = fmaxf(beta, 0.f) + log1pf(__expf(-fabsf(beta)));
    const float sqrt_c = sqrtf(cc);
    const float bneg = -beta_pos / sqrt_c;
    const float bias2 = -bias * 1.442695040888963f;
    const float onepe = 1.f + EPSF;

    const char* KA = KbA + (size_t)b * 524288;
    const char* VtBase = Vtb + (size_t)b * 524288;

    if (tid < 16) {
        float2 x = qng[bS + s0 + tid];
        *(float2*)(smem + 66048 + tid * 8) = x;
    } else if (tid < 32) {
        l_row[tid - 16] = 0.f;
    } else if (tid < 48) {
        nsq_s[tid - 32] = 0.f;
    }

    const int n0 = wn * 16 + lm;
    const char* kaBase = KA + (n0 >> 6) * 16384 + (n0 & 63) * 64 + quad * 16;
    const int foffV = n0 * 64 + quad * 16;
    short8 kf[4];
    float2 yg;
    {
#pragma unroll
        for (int ks = 0; ks < 4; ++ks)
            kf[ks] = *(const short8*)(kaBase + ks * 4096);
        yg = kng[bS + n0];
    }

    short8 aq[4];
    {
        const unsigned short* qrow = Qb + (bS + s0 + lm) * D_;
#pragma unroll
        for (int ks = 0; ks < 4; ++ks)
            aq[ks] = *(const short8*)(qrow + ks * 32 + quad * 8);
    }

    __syncthreads();

    float2 xr4[4];
#pragma unroll
    for (int r = 0; r < 4; ++r)
        xr4[r] = *(const float2*)(smem + 66048 + (quad * 4 + r) * 8);

    f32x4 o = {0.f, 0.f, 0.f, 0.f};
    float lacc[4] = {0.f, 0.f, 0.f, 0.f};

    for (int it = 0; it < 16; ++it) {
        short8 kfn[4], vf[4];
        float2 ygn;
        {
            const char* vb = VtBase + (size_t)it * 32768 + foffV;
#pragma unroll
            for (int ks = 0; ks < 4; ++ks)
                vf[ks] = *(const short8*)(vb + ks * 8192);
        }
        if (it < 15) {
            const char* kb = kaBase + (size_t)(it + 1) * 32768;
#pragma unroll
            for (int ks = 0; ks < 4; ++ks)
                kfn[ks] = *(const short8*)(kb + ks * 4096);
            ygn = kng[bS + (size_t)(it + 1) * 128 + n0];
        }
        __builtin_amdgcn_sched_barrier(0);

        f32x4 acc = {0.f, 0.f, 0.f, 0.f};
#pragma unroll
        for (int ks = 0; ks < 4; ++ks)
            acc = __builtin_amdgcn_mfma_f32_16x16x32_bf16(aq[ks], kf[ks], acc, 0, 0, 0);

#pragma unroll
        for (int r = 0; r < 4; ++r) {
            int row = quad * 4 + r;
            float diff = fmaf(-2.f, acc[r], xr4[r].x + yg.x);
            float arg = fmaxf(fmaf(diff * yg.y, xr4[r].y, 1.f), onepe);
            float w = arg + sqrtf(fmaf(arg, arg, -1.f));
            float pv = __builtin_amdgcn_exp2f(fmaf(bneg, __builtin_amdgcn_logf(w), bias2));
            *(unsigned short*)(smem + row * PRS + (it * 128 + n0) * 2) = f2bf(pv);
            lacc[r] += pv;
        }
        __syncthreads();

        {
            const char* prow = smem + lm * PRS + it * 256 + quad * 16;
#pragma unroll
            for (int ks = 0; ks < 4; ++ks) {
                short8 ap = *(const short8*)(prow + ks * 64);
                o = __builtin_amdgcn_mfma_f32_16x16x32_bf16(ap, vf[ks], o, 0, 0, 0);
            }
        }

        if (it < 15) {
#pragma unroll
            for (int ks = 0; ks < 4; ++ks) kf[ks] = kfn[ks];
            yg = ygn;
        }
    }

#pragma unroll
    for (int r = 0; r < 4; ++r) {
        float s = lacc[r];
#pragma unroll
        for (int m = 1; m <= 8; m <<= 1) s += __shfl_xor(s, m, 64);
        if (lm == 0) atomicAdd(&l_row[quad * 4 + r], s);
    }
    __syncthreads();

    float linv[4];
#pragma unroll
    for (int r = 0; r < 4; ++r) linv[r] = 1.f / l_row[quad * 4 + r];

#pragma unroll
    for (int r = 0; r < 4; ++r) {
        float x = o[r] * linv[r];
        o[r] = x;
        float np = x * x;
#pragma unroll
        for (int m = 1; m <= 8; m <<= 1) np += __shfl_xor(np, m, 64);
        if (lm == 0) atomicAdd(&nsq_s[quad * 4 + r], np);
    }
    __syncthreads();
#pragma unroll
    for (int r = 0; r < 4; ++r) {
        int row = quad * 4 + r;
        float vn = fmaxf(sqrtf(nsq_s[row]), EPSF);
        float a = sqrt_c * vn;
        float th = 1.f - 2.f / (__expf(2.f * a) + 1.f);
        float sc = th / a;
        hout[(bS + s0 + row) * D_ + n0] = o[r] * sc;
    }

    {
        float4* wdst = (float4*)(wout + (bS + s0) * (size_t)S_);
#pragma unroll
        for (int j = 0; j < 8; ++j) {
            int idx = tid + j * 512;
            int row = idx >> 8;
            int ch = idx & 255;
            float lr = 1.f / l_row[row];
            uint4 u = *(const uint4*)(smem + row * PRS + ch * 16);
            float4 f0, f1;
            f0.x = __uint_as_float(u.x << 16) * lr;
            f0.y = __uint_as_float(u.x & 0xffff0000u) * lr;
            f0.z = __uint_as_float(u.y << 16) * lr;
            f0.w = __uint_as_float(u.y & 0xffff0000u) * lr;
            f1.x = __uint_as_float(u.z << 16) * lr;
            f1.y = __uint_as_float(u.z & 0xffff0000u) * lr;
            f1.z = __uint_as_float(u.w << 16) * lr;
            f1.w = __uint_as_float(u.w & 0xffff0000u) * lr;
            wdst[idx * 2] = f0;
            wdst[idx * 2 + 1] = f1;
        }
    }
}

// ===================== launch =====================

extern "C" void kernel_launch(void* const* d_in, const int* in_sizes, int n_in,
                              void* d_out, int out_size, void* d_ws, size_t ws_size,
                              hipStream_t stream) {
    const float* q    = (const float*)d_in[0];
    const float* k    = (const float*)d_in[1];
    const float* v    = (const float*)d_in[2];
    const float* c    = (const float*)d_in[3];
    const float* beta = (const float*)d_in[4];
    const float* ab   = (const float*)d_in[5];

    float* out  = (float*)d_out;
    float* hout = out;                          // (B,S,D)
    float* wout = out + (size_t)B_ * S_ * D_;   // (B,S,S)

    char* wsb = (char*)d_ws;
    float* lws = (float*)(wsb + 65536);
    const size_t QG_OFF = 98304;
    const size_t KG_OFF = QG_OFF + 65536;
    const size_t QB_OFF = KG_OFF + 65536;       // 229376
    const size_t KA_OFF = QB_OFF + 2097152;
    const size_t VT_OFF = KA_OFF + 2097152;
    const size_t T2_END = VT_OFF + 2097152;     // 6520832
    const size_t OP_OFF = T2_END;
    const size_t PW_OFF = OP_OFF + (size_t)4 * B_ * S_ * D_ * 4;   // +16.8 MB
    const size_t NEED1  = PW_OFF + (size_t)B_ * S_ * S_ * 2;       // +33.5 MB

    float2*  qng = (float2*)(wsb + QG_OFF);
    float2*  kng = (float2*)(wsb + KG_OFF);
    unsigned* Qb = (unsigned*)(wsb + QB_OFF);
    unsigned* KbA = (unsigned*)(wsb + KA_OFF);
    uint4*   Vtb = (uint4*)(wsb + VT_OFF);

    convqk_kernel<<<4096, 256, 0, stream>>>(q, k, c, lws, qng, kng, Qb, KbA);
    convv_kernel<<<64, 256, 0, stream>>>(v, Vtb);

    if (ws_size >= NEED1) {
        float* Opart = (float*)(wsb + OP_OFF);
        uint4* Pws   = (uint4*)(wsb + PW_OFF);
        hattn11_kernel<<<1024, 512, 0, stream>>>((const unsigned short*)Qb, (const char*)KbA,
                                                 (const char*)Vtb, qng, kng, c, beta, ab,
                                                 lws, Opart, Pws);
        hepi4_kernel<<<2048, 256, 0, stream>>>(Opart, lws, c, hout);
        wnorm2_kernel<<<8192, 256, 0, stream>>>(Pws, lws, wout);
    } else {
        hattn8_kernel<<<512, 512, 0, stream>>>((const unsigned short*)Qb, (const char*)KbA,
                                               (const char*)Vtb, qng, kng, c, beta, ab,
                                               hout, wout);
    }
}

// Round 11
// 136.255 us; speedup vs baseline: 1.3338x; 1.3338x over previous
//
#include <hip/hip_runtime.h>
#include <math.h>

#define B_ 4
#define S_ 2048
#define D_ 128
#define EPSF 1e-5f
#define BN 128
#define PSB 272     // fallback-path Ps row stride
#define PRS 4112    // v6 P_row stride bytes (2048*2 + 16): 16B-aligned, bank-shifted

typedef __attribute__((ext_vector_type(8))) short short8;
typedef __attribute__((ext_vector_type(4))) float f32x4;

static __device__ __forceinline__ unsigned short f2bf(float f) {
    unsigned u = __float_as_uint(f);
    return (unsigned short)((u + 0x7fffu + ((u >> 16) & 1u)) >> 16);
}

// ===================== pre-pass kernels (shared by both paths) =====================
// ws bytes: [0,32K) qn, [32K,64K) kn, [64K,96K) lws, [96K,160K) qng, [160K,224K) kng,
//           [224K..) Qb(2M) Kb(2M) Vtb(2M)

__global__ __launch_bounds__(256) void convqk_kernel(const float* __restrict__ q,
                                                     const float* __restrict__ k,
                                                     const float* __restrict__ cp,
                                                     float* __restrict__ qn, float* __restrict__ kn,
                                                     float* __restrict__ lws,
                                                     float2* __restrict__ qng, float2* __restrict__ kng,
                                                     unsigned* __restrict__ Qb, unsigned* __restrict__ Kb) {
    int row = blockIdx.x * 4 + (threadIdx.x >> 6);   // one wave per row, 16384 rows
    int lane = threadIdx.x & 63;
    const int NR = B_ * S_;
    const float cc = cp[0];
    bool isQ = row < NR;
    int r = isQ ? row : row - NR;
    float2 v = ((const float2*)(isQ ? q : k))[(size_t)r * 64 + lane];
    unsigned pk = (unsigned)f2bf(v.x) | ((unsigned)f2bf(v.y) << 16);
    float nrm = v.x * v.x + v.y * v.y;
#pragma unroll
    for (int m = 1; m <= 32; m <<= 1) nrm += __shfl_xor(nrm, m, 64);
    if (isQ) {
        Qb[(size_t)r * 64 + lane] = pk;              // plain row-major
        if (lane == 0) {
            qn[r] = nrm;
            qng[r] = make_float2(nrm, 2.f * cc * __builtin_amdgcn_rcpf(1.f - cc * nrm));
        }
        if (lane == 1) lws[r] = 0.f;                 // zero l accumulator (fallback path)
    } else {
        int c = lane >> 2;                           // 16B chunk index 0..15
        int cs = c ^ (r & 7);                        // bank swizzle baked into global layout
        Kb[(size_t)r * 64 + cs * 4 + (lane & 3)] = pk;
        if (lane == 0) {
            kn[r] = nrm;
            kng[r] = make_float2(nrm, __builtin_amdgcn_rcpf(1.f - cc * nrm));
        }
    }
}

__global__ __launch_bounds__(256) void convv_kernel(const float* __restrict__ v, uint4* __restrict__ Vtb) {
    __shared__ unsigned short Vs[128 * 132];
    int b = blockIdx.x >> 4;
    int t = blockIdx.x & 15;
    int tid = threadIdx.x;
    const float* src = v + ((size_t)b * S_ + t * 128) * D_;
    int d4 = tid & 31, key0 = tid >> 5;
#pragma unroll
    for (int it = 0; it < 16; ++it) {
        int key = key0 + it * 8;
        float4 f = *(const float4*)(src + (size_t)key * D_ + d4 * 4);
        unsigned short* dst = &Vs[key * 132 + d4 * 4];
        dst[0] = f2bf(f.x); dst[1] = f2bf(f.y); dst[2] = f2bf(f.z); dst[3] = f2bf(f.w);
    }
    __syncthreads();
    uint4* tile = Vtb + (size_t)blockIdx.x * (128 * 16);   // [tile][d=128][16 x 16B chunks]
    int d = tid & 127;
    int cl = tid >> 7;
#pragma unroll
    for (int it = 0; it < 8; ++it) {
        int c = cl + it * 2;
        int kb = c * 8;
        unsigned short e0 = Vs[(kb + 0) * 132 + d], e1 = Vs[(kb + 1) * 132 + d];
        unsigned short e2 = Vs[(kb + 2) * 132 + d], e3 = Vs[(kb + 3) * 132 + d];
        unsigned short e4 = Vs[(kb + 4) * 132 + d], e5 = Vs[(kb + 5) * 132 + d];
        unsigned short e6 = Vs[(kb + 6) * 132 + d], e7 = Vs[(kb + 7) * 132 + d];
        uint4 o;
        o.x = (unsigned)e0 | ((unsigned)e1 << 16);
        o.y = (unsigned)e2 | ((unsigned)e3 << 16);
        o.z = (unsigned)e4 | ((unsigned)e5 << 16);
        o.w = (unsigned)e6 | ((unsigned)e7 << 16);
        tile[d * 16 + (c ^ (d & 7))] = o;
    }
}

// ===================== v6: full-row P in LDS, K/V fragments direct from global =====================
// One 1024-thread block per 32 q-rows (grid 256, 1 block/CU, 16 waves). P for the whole row
// lives in LDS (32 x 2048 bf16, stride 4112B). K/V MFMA fragments are read straight from the
// pre-swizzled global Kb/Vtb (L2/L3-resident) into registers, software-pipelined: kf(it+1)+yg(it+1)
// issued after QK, vf(it) issued before the dist VALU chain -> all loads complete by the barrier.
// ONE barrier per iteration (each iter writes a disjoint 128-col P stripe; no WAR).
// Tail: l reduction -> O normalize + exp-map + hout -> P_lds -> normalized fp32 W (67 MB, once).
//
// LDS map (132096 B): P_row @0 (32 x 4112), xr @131584 (32 float2), l_row @131840, nsq_s @131968.

__global__ __launch_bounds__(1024, 4) void hattn6_kernel(
    const unsigned short* __restrict__ Qb, const char* __restrict__ Kb, const char* __restrict__ Vtb,
    const float2* __restrict__ qng, const float2* __restrict__ kng,
    const float* __restrict__ cp, const float* __restrict__ betap, const float* __restrict__ biasp,
    float* __restrict__ hout, float* __restrict__ wout) {

    __shared__ __align__(1024) char smem[132096];
    float* l_row = (float*)(smem + 131840);
    float* nsq_s = (float*)(smem + 131968);

    const int tid = threadIdx.x;
    const int lane = tid & 63, wave = tid >> 6;      // 16 waves
    const int wm = wave & 1, wn = wave >> 1;         // wm: 16-row half; wn: 16-col/16-d slice (0..7)
    const int lm = lane & 15, quad = lane >> 4;

    int xcd = blockIdx.x & 7;                        // batches grouped per XCD for L2 locality
    int b = xcd >> 1;
    int rb = (blockIdx.x >> 3) * 2 + (xcd & 1);      // 0..63
    int s0 = rb * 32;
    const size_t bS = (size_t)b * S_;

    const float beta = betap[0], bias = biasp[0];
    const float cc = cp[0];
    const float beta_pos = fmaxf(beta, 0.f) + log1pf(__expf(-fabsf(beta)));
    const float sqrt_c = sqrtf(cc);
    const float bneg = -beta_pos / sqrt_c;           // p = 2^(bneg*log2(w) + bias2)
    const float bias2 = -bias * 1.442695040888963f;
    const float onepe = 1.f + EPSF;

    const char* KbBase = Kb + bS * 256;
    const char* VtBase = Vtb + (size_t)b * 16 * 32768;

    // ---- prologue: tables to LDS; issue K frags + key norms for tile 0 ----
    if (tid < 32) {
        float2 x = qng[bS + s0 + tid];
        *(float2*)(smem + 131584 + tid * 8) = x;
    } else if (tid < 64) {
        l_row[tid - 32] = 0.f;
    } else if (tid < 96) {
        nsq_s[tid - 64] = 0.f;
    }

    const int n0 = wn * 16 + lm;                     // key col (QK) / d index (PV)
    short8 kf[4];
    float2 yg;
    {
        const char* kb0 = KbBase + n0 * 256;
#pragma unroll
        for (int ks = 0; ks < 4; ++ks) {
            int c = ks * 4 + quad;
            kf[ks] = *(const short8*)(kb0 + ((c ^ (n0 & 7)) * 16));
        }
        yg = kng[bS + n0];
    }

    // Q A-frags in registers (A: m=lane&15, k=quad*8+j)
    short8 aq[4];
    {
        const unsigned short* qrow = Qb + (bS + s0 + wm * 16 + lm) * D_;
#pragma unroll
        for (int ks = 0; ks < 4; ++ks)
            aq[ks] = *(const short8*)(qrow + ks * 32 + quad * 8);
    }

    __syncthreads();   // tables visible

    // per-row constants, hoisted out of the loop
    float2 xr4[4];
#pragma unroll
    for (int r = 0; r < 4; ++r)
        xr4[r] = *(const float2*)(smem + 131584 + (wm * 16 + quad * 4 + r) * 8);

    f32x4 o = {0.f, 0.f, 0.f, 0.f};
    float lacc[4] = {0.f, 0.f, 0.f, 0.f};

    for (int it = 0; it < 16; ++it) {
        // ---- S = Q K^T (wave tile 16x16) ----
        f32x4 acc = {0.f, 0.f, 0.f, 0.f};
#pragma unroll
        for (int ks = 0; ks < 4; ++ks)
            acc = __builtin_amdgcn_mfma_f32_16x16x32_bf16(aq[ks], kf[ks], acc, 0, 0, 0);

        // ---- issue next-tile K frags + key norms (hidden under dist + PV) ----
        short8 kfn[4];
        float2 ygn;
        if (it < 15) {
            const char* kb = KbBase + (size_t)(it + 1) * 32768 + n0 * 256;
#pragma unroll
            for (int ks = 0; ks < 4; ++ks) {
                int c = ks * 4 + quad;
                kfn[ks] = *(const short8*)(kb + ((c ^ (n0 & 7)) * 16));
            }
            ygn = kng[bS + (size_t)(it + 1) * 128 + n0];
        }

        // ---- issue current-tile V frags (hidden under dist VALU) ----
        short8 vf[4];
        {
            const char* vb = VtBase + (size_t)it * 32768 + n0 * 256;
#pragma unroll
            for (int ks = 0; ks < 4; ++ks) {
                int c = ks * 4 + quad;
                vf[ks] = *(const short8*)(vb + ((c ^ (n0 & 7)) * 16));
            }
        }

        // ---- dist -> p = exp2(bneg*log2(arg+sqrt(arg^2-1)) + bias2), unnormalized ----
#pragma unroll
        for (int r = 0; r < 4; ++r) {
            int row = wm * 16 + quad * 4 + r;        // C/D layout: row=(lane>>4)*4+reg
            float diff = fmaf(-2.f, acc[r], xr4[r].x + yg.x);
            float arg = fmaf(diff * yg.y, xr4[r].y, 1.f);
            arg = fmaxf(arg, onepe);
            float w = arg + sqrtf(fmaf(arg, arg, -1.f));
            float pv = __builtin_amdgcn_exp2f(fmaf(bneg, __builtin_amdgcn_logf(w), bias2));
            *(unsigned short*)(smem + row * PRS + (it * 128 + n0) * 2) = f2bf(pv);
            lacc[r] += pv;
        }
        __syncthreads();   // P stripe visible (loads already near-complete -> cheap drain)

        // ---- O += P V (wave tile 16 rows x 16 d, K=128 keys) ----
        {
            const char* prow = smem + (wm * 16 + lm) * PRS + it * 256 + quad * 16;
#pragma unroll
            for (int ks = 0; ks < 4; ++ks) {
                short8 ap = *(const short8*)(prow + ks * 64);
                o = __builtin_amdgcn_mfma_f32_16x16x32_bf16(ap, vf[ks], o, 0, 0, 0);
            }
        }

        if (it < 15) {
#pragma unroll
            for (int ks = 0; ks < 4; ++ks) kf[ks] = kfn[ks];
            yg = ygn;
        }
    }

    // ---- l reduction: per-thread register sums -> 16-lane shfl -> LDS atomics ----
#pragma unroll
    for (int r = 0; r < 4; ++r) {
        float s = lacc[r];
#pragma unroll
        for (int m = 1; m <= 8; m <<= 1) s += __shfl_xor(s, m, 64);
        if (lm == 0) atomicAdd(&l_row[wm * 16 + quad * 4 + r], s);
    }
    __syncthreads();

    float linv[4];
#pragma unroll
    for (int r = 0; r < 4; ++r) linv[r] = 1.f / l_row[wm * 16 + quad * 4 + r];

    // ---- O normalize + exp-map + hout ----
#pragma unroll
    for (int r = 0; r < 4; ++r) {
        float x = o[r] * linv[r];
        o[r] = x;
        float np = x * x;
#pragma unroll
        for (int m = 1; m <= 8; m <<= 1) np += __shfl_xor(np, m, 64);
        if (lm == 0) atomicAdd(&nsq_s[wm * 16 + quad * 4 + r], np);
    }
    __syncthreads();
#pragma unroll
    for (int r = 0; r < 4; ++r) {
        int row = wm * 16 + quad * 4 + r;
        float vn = fmaxf(sqrtf(nsq_s[row]), EPSF);
        float a = sqrt_c * vn;
        float th = 1.f - 2.f / (__expf(2.f * a) + 1.f);  // tanh(a)
        float sc = th / a;                                // tanh(sqrt_c*vn)/(sqrt_c*vn)
        hout[(bS + s0 + row) * D_ + n0] = o[r] * sc;
    }

    // ---- P_lds -> normalized fp32 W, single coalesced write (32 x 2048 = 256 KB/block) ----
    {
        float4* wdst = (float4*)(wout + (bS + s0) * (size_t)S_);
#pragma unroll
        for (int j = 0; j < 8; ++j) {
            int idx = tid + j * 1024;                // 8192 chunks = 32 rows x 256
            int row = idx >> 8;
            int ch = idx & 255;
            float lr = 1.f / l_row[row];
            uint4 u = *(const uint4*)(smem + row * PRS + ch * 16);
            float4 f0, f1;
            f0.x = __uint_as_float(u.x << 16) * lr;
            f0.y = __uint_as_float(u.x & 0xffff0000u) * lr;
            f0.z = __uint_as_float(u.y << 16) * lr;
            f0.w = __uint_as_float(u.y & 0xffff0000u) * lr;
            f1.x = __uint_as_float(u.z << 16) * lr;
            f1.y = __uint_as_float(u.z & 0xffff0000u) * lr;
            f1.z = __uint_as_float(u.w << 16) * lr;
            f1.w = __uint_as_float(u.w & 0xffff0000u) * lr;
            wdst[idx * 2] = f0;
            wdst[idx * 2 + 1] = f1;
        }
    }
}

// ===================== round-2 path (proven, ws fallback) =====================

__global__ __launch_bounds__(512, 2) void hattn_kernel(
    const unsigned short* __restrict__ Qb, const char* __restrict__ Kb, const char* __restrict__ Vtb,
    const float* __restrict__ qn, const float* __restrict__ kn,
    const float* __restrict__ cp, const float* __restrict__ betap, const float* __restrict__ biasp,
    float* __restrict__ lws, float* __restrict__ houtg, float* __restrict__ woutg) {

    __shared__ __align__(1024) char smem[75136];
    char* KsB = smem;
    char* VtB = smem + 32768;
    char* PsB = smem + 65536;
    float* kn_s  = (float*)(smem + 74240);
    float* qn_s  = (float*)(smem + 74752);
    float* l_row = (float*)(smem + 74880);
    float* nsq_s = (float*)(smem + 75008);

    const int tid = threadIdx.x;
    const int lane = tid & 63, wave = tid >> 6;
    const int wm = wave & 1, wn = wave >> 1;
    const int lm = lane & 15, quad = lane >> 4;

    int xcd = blockIdx.x & 7;
    int b = xcd >> 1;
    int rb = (blockIdx.x >> 3) * 2 + (xcd & 1);
    int s0 = rb * 32;
    const size_t bS = (size_t)b * S_;

    const float cc = cp[0], beta = betap[0], bias = biasp[0];
    const float beta_pos = fmaxf(beta, 0.f) + log1pf(__expf(-fabsf(beta)));
    const float sqrt_c = sqrtf(cc);
    const float inv_sqrt_c = 1.f / sqrt_c;

    if (tid < 32) {
        qn_s[tid] = qn[bS + s0 + tid];
        l_row[tid] = 0.f;
        nsq_s[tid] = 0.f;
    }

    short8 aq[4];
    {
        const unsigned short* qrow = Qb + (bS + s0 + wm * 16 + lm) * D_;
#pragma unroll
        for (int ks = 0; ks < 4; ++ks)
            aq[ks] = *(const short8*)(qrow + ks * 32 + quad * 8);
    }

    f32x4 o0 = {0.f, 0.f, 0.f, 0.f}, o1 = {0.f, 0.f, 0.f, 0.f};

    const char* KbBase = Kb + bS * 256;
    const char* VtBase = Vtb + (size_t)b * 16 * 32768;

    for (int t = 0; t < S_ / BN; ++t) {
        int t0 = t * BN;
        __syncthreads();
        {
            const uint4* ksrc = (const uint4*)(KbBase + (size_t)t0 * 256);
            const uint4* vsrc = (const uint4*)(VtBase + (size_t)t * 32768);
            uint4* kd = (uint4*)KsB;
            uint4* vd = (uint4*)VtB;
#pragma unroll
            for (int i = 0; i < 4; ++i) {
                kd[tid + i * 512] = ksrc[tid + i * 512];
                vd[tid + i * 512] = vsrc[tid + i * 512];
            }
            if (tid < BN) kn_s[tid] = kn[bS + t0 + tid];
        }
        __syncthreads();

        f32x4 acc0 = {0.f, 0.f, 0.f, 0.f}, acc1 = {0.f, 0.f, 0.f, 0.f};
#pragma unroll
        for (int ks = 0; ks < 4; ++ks) {
            int n0 = wn * 32 + lm;
            int c = ks * 4 + quad;
            short8 b0 = *(const short8*)(KsB + n0 * 256 + ((c ^ (n0 & 7)) * 16));
            int n1 = n0 + 16;
            short8 b1 = *(const short8*)(KsB + n1 * 256 + ((c ^ (n1 & 7)) * 16));
            acc0 = __builtin_amdgcn_mfma_f32_16x16x32_bf16(aq[ks], b0, acc0, 0, 0, 0);
            acc1 = __builtin_amdgcn_mfma_f32_16x16x32_bf16(aq[ks], b1, acc1, 0, 0, 0);
        }

        float lp[4];
#pragma unroll
        for (int r = 0; r < 4; ++r) {
            int row = wm * 16 + quad * 4 + r;
            float xn = qn_s[row];
            float fx = 1.f - cc * xn;
            float p0, p1;
#pragma unroll
            for (int nt = 0; nt < 2; ++nt) {
                int col = wn * 32 + nt * 16 + lm;
                float dot = (nt == 0) ? acc0[r] : acc1[r];
                float yn = kn_s[col];
                float diff = xn - 2.f * dot + yn;
                float den = fmaxf(fx * (1.f - cc * yn), EPSF);
                float arg = fmaf(2.f * cc * diff, __builtin_amdgcn_rcpf(den), 1.f);
                arg = fmaxf(arg, 1.f + EPSF);
                float dist = __logf(arg + sqrtf(arg * arg - 1.f)) * inv_sqrt_c;
                float p = __expf(fmaf(-beta_pos, dist, -bias));
                woutg[(bS + s0 + row) * S_ + t0 + col] = p;
                *(unsigned short*)(PsB + row * PSB + col * 2) = f2bf(p);
                if (nt == 0) p0 = p; else p1 = p;
            }
            lp[r] = p0 + p1;
        }
#pragma unroll
        for (int r = 0; r < 4; ++r) {
            float s = lp[r];
#pragma unroll
            for (int m = 1; m <= 8; m <<= 1) s += __shfl_xor(s, m, 64);
            if (lm == 0) atomicAdd(&l_row[wm * 16 + quad * 4 + r], s);
        }
        __syncthreads();

#pragma unroll
        for (int ks = 0; ks < 4; ++ks) {
            short8 ap = *(const short8*)(PsB + (wm * 16 + lm) * PSB + (ks * 32 + quad * 8) * 2);
            int d0 = wn * 32 + lm;
            int c = ks * 4 + quad;
            short8 v0 = *(const short8*)(VtB + d0 * 256 + ((c ^ (d0 & 7)) * 16));
            int d1 = d0 + 16;
            short8 v1 = *(const short8*)(VtB + d1 * 256 + ((c ^ (d1 & 7)) * 16));
            o0 = __builtin_amdgcn_mfma_f32_16x16x32_bf16(ap, v0, o0, 0, 0, 0);
            o1 = __builtin_amdgcn_mfma_f32_16x16x32_bf16(ap, v1, o1, 0, 0, 0);
        }
    }
    __syncthreads();

    float xs0[4], xs1[4];
#pragma unroll
    for (int r = 0; r < 4; ++r) {
        int row = wm * 16 + quad * 4 + r;
        float linv = __builtin_amdgcn_rcpf(l_row[row]);
        float x0 = o0[r] * linv, x1 = o1[r] * linv;
        xs0[r] = x0; xs1[r] = x1;
        float np = x0 * x0 + x1 * x1;
#pragma unroll
        for (int m = 1; m <= 8; m <<= 1) np += __shfl_xor(np, m, 64);
        if (lm == 0) atomicAdd(&nsq_s[row], np);
    }
    if (tid < 32) lws[bS + s0 + tid] = l_row[tid];
    __syncthreads();
#pragma unroll
    for (int r = 0; r < 4; ++r) {
        int row = wm * 16 + quad * 4 + r;
        float vn = fmaxf(sqrtf(nsq_s[row]), EPSF);
        float a = sqrt_c * vn;
        float th = 1.f - 2.f * __builtin_amdgcn_rcpf(__expf(2.f * a) + 1.f);
        float sc = th / a;
        houtg[(bS + s0 + row) * D_ + wn * 32 + lm] = xs0[r] * sc;
        houtg[(bS + s0 + row) * D_ + wn * 32 + 16 + lm] = xs1[r] * sc;
    }
}

__global__ __launch_bounds__(256) void wnorm_kernel(float* __restrict__ w,
                                                    const float* __restrict__ lws) {
    size_t idx = (size_t)blockIdx.x * 256 + threadIdx.x;
    int row = (int)(idx >> 9);
    float linv = 1.f / lws[row];
    float4* p = (float4*)w + idx;
    float4 v = *p;
    v.x *= linv; v.y *= linv; v.z *= linv; v.w *= linv;
    *p = v;
}

// ===================== launch =====================

extern "C" void kernel_launch(void* const* d_in, const int* in_sizes, int n_in,
                              void* d_out, int out_size, void* d_ws, size_t ws_size,
                              hipStream_t stream) {
    const float* q    = (const float*)d_in[0];
    const float* k    = (const float*)d_in[1];
    const float* v    = (const float*)d_in[2];
    const float* c    = (const float*)d_in[3];
    const float* beta = (const float*)d_in[4];
    const float* ab   = (const float*)d_in[5];

    float* out  = (float*)d_out;
    float* hout = out;                          // (B,S,D)
    float* wout = out + (size_t)B_ * S_ * D_;   // (B,S,S)

    float* qn  = (float*)d_ws;
    float* kn  = qn + B_ * S_;
    float* lws = kn + B_ * S_;
    char*  wsb = (char*)d_ws;
    const size_t QG_OFF = 98304;
    const size_t KG_OFF = QG_OFF + 65536;
    const size_t QB_OFF = KG_OFF + 65536;       // 229376
    const size_t KB_OFF = QB_OFF + 2097152;
    const size_t VT_OFF = KB_OFF + 2097152;
    const size_t NEED1  = VT_OFF + 2097152;

    float2*  qng = (float2*)(wsb + QG_OFF);
    float2*  kng = (float2*)(wsb + KG_OFF);
    unsigned* Qb = (unsigned*)(wsb + QB_OFF);
    unsigned* Kb = (unsigned*)(wsb + KB_OFF);
    uint4*   Vtb = (uint4*)(wsb + VT_OFF);

    if (ws_size >= NEED1) {
        convqk_kernel<<<4096, 256, 0, stream>>>(q, k, c, qn, kn, lws, qng, kng, Qb, Kb);
        convv_kernel<<<64, 256, 0, stream>>>(v, Vtb);
        hattn6_kernel<<<256, 1024, 0, stream>>>((const unsigned short*)Qb, (const char*)Kb,
                                                (const char*)Vtb, qng, kng, c, beta, ab,
                                                hout, wout);
    } else {
        convqk_kernel<<<4096, 256, 0, stream>>>(q, k, c, qn, kn, lws, qng, kng, Qb, Kb);
        convv_kernel<<<64, 256, 0, stream>>>(v, Vtb);
        hattn_kernel<<<256, 512, 0, stream>>>((const unsigned short*)Qb, (const char*)Kb,
                                              (const char*)Vtb, qn, kn, c, beta, ab,
                                              lws, hout, wout);
        wnorm_kernel<<<(B_ * S_ * S_ / 4) / 256, 256, 0, stream>>>(wout, lws);
    }
}